// Round 8
// baseline (153.472 us; speedup 1.0000x reference)
//
#include <hip/hip_runtime.h>
#include <hip/hip_bf16.h>

#define B_DIM 2048
#define S_DIM 32768
#define G_DIM 4096
#define E_DIM 1024
#define ROWS_PER_BLK 4

typedef __bf16 bf16x8 __attribute__((ext_vector_type(8)));
typedef float f32x4 __attribute__((ext_vector_type(4)));

__device__ __forceinline__ unsigned short f2bf(float f) {
  unsigned int u = __builtin_bit_cast(unsigned int, f);
  u += 0x7FFFu + ((u >> 16) & 1u);   // round-to-nearest-even (no NaN inputs here)
  return (unsigned short)(u >> 16);
}

__device__ __forceinline__ void async16(void* lds, const void* g) {
  __builtin_amdgcn_global_load_lds(
      (const __attribute__((address_space(1))) unsigned int*)g,
      (__attribute__((address_space(3))) unsigned int*)lds, 16, 0, 0);
}

// Non-returning LDS float atomic add (ds_add_f32). Invisible to the
// compiler's waitcnt model: must be drained with an explicit
// s_waitcnt lgkmcnt(0) before any barrier that readers wait on.
__device__ __forceinline__ void lds_add(float* p, float v) {
  unsigned off = (unsigned)(size_t)(__attribute__((address_space(3))) float*)p;
  asm volatile("ds_add_f32 %0, %1" :: "v"(off), "v"(v));
}

__device__ __forceinline__ uint2 pack4bf(float4 v) {
  uint2 r;
  r.x = (unsigned)__builtin_bit_cast(unsigned short, (__bf16)v.x) |
        ((unsigned)__builtin_bit_cast(unsigned short, (__bf16)v.y) << 16);
  r.y = (unsigned)__builtin_bit_cast(unsigned short, (__bf16)v.z) |
        ((unsigned)__builtin_bit_cast(unsigned short, (__bf16)v.w) << 16);
  return r;
}

// ---------------- setup A: per-element packed meta --------------------------
// meta1[s] = perm[s] (15b) | orflag (bit15) | bf16(cm) (bits16-31)
__global__ __launch_bounds__(256) void setup_meta(
    const float* __restrict__ w_elem, const int* __restrict__ perm,
    const int* __restrict__ segid, const int* __restrict__ agg,
    unsigned* __restrict__ meta1) {
  int s = blockIdx.x * 256 + threadIdx.x;
  if (s >= S_DIM) return;
  int g = segid[s];
  int a = agg[g];
  float cm = (a == 0) ? 1.0f : (a == 2 ? w_elem[s] : 0.0f);
  meta1[s] = (unsigned)perm[s] | (a == 1 ? 0x8000u : 0u) |
             ((unsigned)f2bf(cm) << 16);
}

// ---------------- setup B: per-32-window run-head mask + first group -------
__global__ __launch_bounds__(256) void setup_runs(
    const int* __restrict__ segid, unsigned* __restrict__ metaH,
    unsigned short* __restrict__ metaG) {
  int t = blockIdx.x * 256 + threadIdx.x;
  if (t >= S_DIM / 32) return;
  int s0 = t * 32;
  int prev = (s0 == 0) ? -1 : segid[s0 - 1];
  unsigned m = 0;
#pragma unroll
  for (int c = 0; c < 8; ++c) {
    int4 gw = *reinterpret_cast<const int4*>(segid + s0 + c * 4);
    if (gw.x != prev) m |= 1u << (c * 4 + 0);
    if (gw.y != gw.x) m |= 1u << (c * 4 + 1);
    if (gw.z != gw.y) m |= 1u << (c * 4 + 2);
    if (gw.w != gw.z) m |= 1u << (c * 4 + 3);
    prev = gw.w;
  }
  metaH[t] = m;
  metaG[t] = (unsigned short)segid[s0];
}

// ---------------- W (f32, [E][G]) -> bf16 ----------------
__global__ __launch_bounds__(256) void conv_w(const float* __restrict__ W,
                                              unsigned short* __restrict__ Wb) {
  size_t i = ((size_t)blockIdx.x * 256 + threadIdx.x) * 4;
  float4 v = *reinterpret_cast<const float4*>(W + i);
  ushort4 o;
  o.x = f2bf(v.x);
  o.y = f2bf(v.y);
  o.z = f2bf(v.z);
  o.w = f2bf(v.w);
  *reinterpret_cast<ushort4*>(Wb + i) = o;
}

// ---------------- stage 1: 4 rows/block, T14 pipelined ---------------------
// 1024 threads, 80 KB LDS -> 2 blocks/CU (launch_bounds(1024,8) caps VGPR=64).
// Per row-iteration: ISSUE next row's 8 float4 loads + pack to bf16 regs
// (latency hides under the walk), WALK current row (run-combined, R6 logic),
// barrier, then ds_write the staged row + finalize current row from acc.
__global__ __launch_bounds__(1024, 8) void seg_reduce(
    const float* __restrict__ x, const unsigned* __restrict__ meta1,
    const unsigned* __restrict__ metaH, const unsigned short* __restrict__ metaG,
    const int* __restrict__ agg, unsigned short* __restrict__ y) {
  __shared__ unsigned short xrow[S_DIM];  // 64 KB (bf16)
  __shared__ float acc[G_DIM];            // 16 KB
  const int t = threadIdx.x;
  const int b0 = blockIdx.x * ROWS_PER_BLK;

  // hoisted per-block invariants
  const int s0 = t * 32;
  const unsigned mrun = metaH[t];
  const bool firstPlain = (mrun & 1u) != 0;  // first run starts at s0
  const unsigned g0 = metaG[t];
  const int a0 = agg[t];
  const int a1 = agg[t + 1024];
  const int a2 = agg[t + 2048];
  const int a3 = agg[t + 3072];

#pragma unroll
  for (int i = 0; i < G_DIM / 1024; ++i) acc[t + i * 1024] = 0.0f;

  // prologue: stage row 0 (unoverlapped)
  {
    const float4* xg = reinterpret_cast<const float4*>(x + (size_t)b0 * S_DIM);
#pragma unroll
    for (int k = 0; k < 8; ++k) {
      uint2 p = pack4bf(xg[k * 1024 + t]);
      *reinterpret_cast<uint2*>(&xrow[(k * 1024 + t) * 4]) = p;
    }
  }
  __syncthreads();

  for (int i = 0; i < ROWS_PER_BLK; ++i) {
    // ---- issue next row's loads; pack to 16 registers (uint2 x 8) ----
    uint2 sv[8];
    if (i < ROWS_PER_BLK - 1) {
      const float4* xgn =
          reinterpret_cast<const float4*>(x + (size_t)(b0 + i + 1) * S_DIM);
#pragma unroll
      for (int k = 0; k < 8; ++k) sv[k] = pack4bf(xgn[k * 1024 + t]);
    }

    // ---- walk current row (R6 run-combine logic, quartered) ----
    unsigned g = g0;
    float sum = 0.0f;
    int nflush = 0;
#pragma unroll
    for (int q = 0; q < 4; ++q) {
      const int sb = s0 + q * 8;
      uint4 ma = *reinterpret_cast<const uint4*>(meta1 + sb);
      uint4 mb = *reinterpret_cast<const uint4*>(meta1 + sb + 4);
      unsigned m[8] = {ma.x, ma.y, ma.z, ma.w, mb.x, mb.y, mb.z, mb.w};
      unsigned short xu[8];
#pragma unroll
      for (int j = 0; j < 8; ++j) xu[j] = xrow[m[j] & 0x7FFF];
      const unsigned mh = mrun >> (q * 8);
#pragma unroll
      for (int j = 0; j < 8; ++j) {
        if (q * 8 + j > 0 && (mh & (1u << j))) {  // run head: flush prev run
          if (nflush == 0 && !firstPlain) {
            lds_add(&acc[g], sum);  // first run extends into prev thread
          } else {
            acc[g] = sum;  // exclusively-owned run
          }
          ++nflush;
          sum = 0.0f;
          ++g;
        }
        float xv = __builtin_bit_cast(float, (unsigned)xu[j] << 16);
        float cm = __builtin_bit_cast(float, m[j] & 0xFFFF0000u);
        float v = (m[j] & 0x8000u) ? (xu[j] ? 1.0f : 0.0f) : xv * cm;
        sum += v;
      }
    }
    lds_add(&acc[g], sum);  // last run may extend into next thread

    // drain asm ds_adds (invisible to compiler waitcnt model) before barrier
    asm volatile("s_waitcnt lgkmcnt(0)" ::: "memory");
    __syncthreads();

    // ---- write staged next row into xrow (safe: post-barrier) ----
    if (i < ROWS_PER_BLK - 1) {
#pragma unroll
      for (int k = 0; k < 8; ++k)
        *reinterpret_cast<uint2*>(&xrow[(k * 1024 + t) * 4]) = sv[k];
    }

    // ---- finalize current row + rezero acc ----
    {
      const size_t yb = (size_t)(b0 + i) * G_DIM;
      float v0 = acc[t];
      float v1 = acc[t + 1024];
      float v2 = acc[t + 2048];
      float v3 = acc[t + 3072];
      if (a0 == 1) v0 = (v0 > 0.0f) ? 1.0f : 0.0f;
      if (a1 == 1) v1 = (v1 > 0.0f) ? 1.0f : 0.0f;
      if (a2 == 1) v2 = (v2 > 0.0f) ? 1.0f : 0.0f;
      if (a3 == 1) v3 = (v3 > 0.0f) ? 1.0f : 0.0f;
      y[yb + t] = f2bf(fmaxf(v0, 0.0f));
      y[yb + t + 1024] = f2bf(fmaxf(v1, 0.0f));
      y[yb + t + 2048] = f2bf(fmaxf(v2, 0.0f));
      y[yb + t + 3072] = f2bf(fmaxf(v3, 0.0f));
      acc[t] = 0.0f;
      acc[t + 1024] = 0.0f;
      acc[t + 2048] = 0.0f;
      acc[t + 3072] = 0.0f;
    }
    __syncthreads();
  }
}

// ---------------- stage 2: out[b,e] = sum_g yr[b,g] * W[e,g]  (bf16 MFMA) --
__global__ __launch_bounds__(256) void gemm_bt(
    const unsigned short* __restrict__ A,   // y bf16 [B_DIM][G_DIM]
    const unsigned short* __restrict__ Bw,  // W bf16 [E_DIM][G_DIM]
    float* __restrict__ C) {                // out f32 [B_DIM][E_DIM]
  __shared__ __align__(16) unsigned short As[64 * 64];  // 8 KB
  __shared__ __align__(16) unsigned short Bs[64 * 64];  // 8 KB
  const int t = threadIdx.x;
  const int lane = t & 63;
  const int wid = t >> 6;
  const int wr = wid >> 1;  // wave row (M)
  const int wc = wid & 1;   // wave col (N)
  const int row0 = blockIdx.y * 64;
  const int col0 = blockIdx.x * 64;

  // staging: thread t covers LDS byte t*16 -> (row=t>>3, slot=t&7)
  const int r_ = t >> 3;  // 0..31
  const int s_ = t & 7;
  const int ksw = (s_ ^ (r_ & 7)) * 8;  // inverse-swizzled k offset (elements)
  const unsigned short* Ag0 = A + (size_t)(row0 + r_) * G_DIM + ksw;
  const unsigned short* Ag1 = A + (size_t)(row0 + r_ + 32) * G_DIM + ksw;
  const unsigned short* Bg0 = Bw + (size_t)(col0 + r_) * G_DIM + ksw;
  const unsigned short* Bg1 = Bw + (size_t)(col0 + r_ + 32) * G_DIM + ksw;

  char* AsB = (char*)As;
  char* BsB = (char*)Bs;
  char* dA0 = AsB + wid * 1024;          // wave-uniform LDS dst bases
  char* dA1 = AsB + 4096 + wid * 1024;
  char* dB0 = BsB + wid * 1024;
  char* dB1 = BsB + 4096 + wid * 1024;

  const int lm = lane & 15;
  const int lk = lane >> 4;  // 0..3

  f32x4 acc[2][2] = {};

  for (int kt = 0; kt < G_DIM; kt += 64) {
    async16(dA0, Ag0 + kt);
    async16(dA1, Ag1 + kt);
    async16(dB0, Bg0 + kt);
    async16(dB1, Bg1 + kt);
    __syncthreads();  // drains vmcnt before barrier
#pragma unroll
    for (int kk = 0; kk < 2; ++kk) {
      bf16x8 af[2], bfr[2];
#pragma unroll
      for (int m = 0; m < 2; ++m) {
        int row = wr * 32 + m * 16 + lm;
        int slot = (kk * 4 + lk) ^ (row & 7);
        af[m] = *(const bf16x8*)(AsB + row * 128 + slot * 16);
      }
#pragma unroll
      for (int n = 0; n < 2; ++n) {
        int row = wc * 32 + n * 16 + lm;
        int slot = (kk * 4 + lk) ^ (row & 7);
        bfr[n] = *(const bf16x8*)(BsB + row * 128 + slot * 16);
      }
#pragma unroll
      for (int m = 0; m < 2; ++m)
#pragma unroll
        for (int n = 0; n < 2; ++n)
          acc[m][n] = __builtin_amdgcn_mfma_f32_16x16x32_bf16(af[m], bfr[n],
                                                              acc[m][n], 0, 0, 0);
    }
    __syncthreads();  // protect LDS before next stage
  }

  // C/D layout: col = lane&15, row = (lane>>4)*4 + reg
#pragma unroll
  for (int m = 0; m < 2; ++m) {
    int r = row0 + wr * 32 + m * 16 + lk * 4;
#pragma unroll
    for (int n = 0; n < 2; ++n) {
      int c = col0 + wc * 32 + n * 16 + lm;
#pragma unroll
      for (int q = 0; q < 4; ++q) {
        C[(size_t)(r + q) * E_DIM + c] = acc[m][n][q];
      }
    }
  }
}

extern "C" void kernel_launch(void* const* d_in, const int* in_sizes, int n_in,
                              void* d_out, int out_size, void* d_ws, size_t ws_size,
                              hipStream_t stream) {
  const float* x = (const float*)d_in[0];
  const float* W = (const float*)d_in[1];
  const float* w_elem = (const float*)d_in[2];
  const int* perm = (const int*)d_in[3];
  const int* segid = (const int*)d_in[4];
  const int* agg = (const int*)d_in[5];
  float* out = (float*)d_out;

  char* ws = (char*)d_ws;
  unsigned short* y = (unsigned short*)ws;  // B*G bf16 = 16 MB
  unsigned short* Wb =
      (unsigned short*)(ws + (size_t)B_DIM * G_DIM * 2);  // E*G bf16 = 8 MB
  unsigned* meta1 =
      (unsigned*)(ws + (size_t)B_DIM * G_DIM * 2 + (size_t)E_DIM * G_DIM * 2);
  unsigned* metaH = (unsigned*)((char*)meta1 + (size_t)S_DIM * 4);
  unsigned short* metaG = (unsigned short*)((char*)metaH + (S_DIM / 32) * 4);

  hipLaunchKernelGGL(setup_meta, dim3(S_DIM / 256), dim3(256), 0, stream,
                     w_elem, perm, segid, agg, meta1);
  hipLaunchKernelGGL(setup_runs, dim3((S_DIM / 32) / 256), dim3(256), 0,
                     stream, segid, metaH, metaG);
  hipLaunchKernelGGL(conv_w, dim3((E_DIM * G_DIM / 4) / 256), dim3(256), 0,
                     stream, W, Wb);
  hipLaunchKernelGGL(seg_reduce, dim3(B_DIM / ROWS_PER_BLK), dim3(1024), 0,
                     stream, x, meta1, metaH, metaG, agg, y);
  hipLaunchKernelGGL(gemm_bt, dim3(E_DIM / 64, B_DIM / 64), dim3(256), 0,
                     stream, y, Wb, out);
}

// Round 9
// 130.037 us; speedup vs baseline: 1.1802x; 1.1802x over previous
//
#include <hip/hip_runtime.h>
#include <hip/hip_bf16.h>

#define B_DIM 2048
#define S_DIM 32768
#define G_DIM 4096
#define E_DIM 1024
#define KSPLIT 4
#define KCHUNK (G_DIM / KSPLIT)

typedef __bf16 bf16x8 __attribute__((ext_vector_type(8)));
typedef float f32x4 __attribute__((ext_vector_type(4)));

__device__ __forceinline__ unsigned short f2bf(float f) {
  unsigned int u = __builtin_bit_cast(unsigned int, f);
  u += 0x7FFFu + ((u >> 16) & 1u);   // round-to-nearest-even (no NaN inputs here)
  return (unsigned short)(u >> 16);
}

__device__ __forceinline__ void async16(void* lds, const void* g) {
  __builtin_amdgcn_global_load_lds(
      (const __attribute__((address_space(1))) unsigned int*)g,
      (__attribute__((address_space(3))) unsigned int*)lds, 16, 0, 0);
}

// Non-returning LDS float atomic add (ds_add_f32). Invisible to the
// compiler's waitcnt model: must be drained with an explicit
// s_waitcnt lgkmcnt(0) before any barrier that readers wait on.
__device__ __forceinline__ void lds_add(float* p, float v) {
  unsigned off = (unsigned)(size_t)(__attribute__((address_space(3))) float*)p;
  asm volatile("ds_add_f32 %0, %1" :: "v"(off), "v"(v));
}

// ---------------- setup A: per-element packed meta --------------------------
// meta1[s] = perm[s] (15b) | orflag (bit15) | bf16(cm) (bits16-31)
__global__ __launch_bounds__(256) void setup_meta(
    const float* __restrict__ w_elem, const int* __restrict__ perm,
    const int* __restrict__ segid, const int* __restrict__ agg,
    unsigned* __restrict__ meta1) {
  int s = blockIdx.x * 256 + threadIdx.x;
  if (s >= S_DIM) return;
  int g = segid[s];
  int a = agg[g];
  float cm = (a == 0) ? 1.0f : (a == 2 ? w_elem[s] : 0.0f);
  meta1[s] = (unsigned)perm[s] | (a == 1 ? 0x8000u : 0u) |
             ((unsigned)f2bf(cm) << 16);
}

// ---------------- setup B: per-32-window run-head mask + first group -------
__global__ __launch_bounds__(256) void setup_runs(
    const int* __restrict__ segid, unsigned* __restrict__ metaH,
    unsigned short* __restrict__ metaG) {
  int t = blockIdx.x * 256 + threadIdx.x;
  if (t >= S_DIM / 32) return;
  int s0 = t * 32;
  int prev = (s0 == 0) ? -1 : segid[s0 - 1];
  unsigned m = 0;
#pragma unroll
  for (int c = 0; c < 8; ++c) {
    int4 gw = *reinterpret_cast<const int4*>(segid + s0 + c * 4);
    if (gw.x != prev) m |= 1u << (c * 4 + 0);
    if (gw.y != gw.x) m |= 1u << (c * 4 + 1);
    if (gw.z != gw.y) m |= 1u << (c * 4 + 2);
    if (gw.w != gw.z) m |= 1u << (c * 4 + 3);
    prev = gw.w;
  }
  metaH[t] = m;
  metaG[t] = (unsigned short)segid[s0];
}

// ---------------- W (f32, [E][G]) -> bf16 ----------------
__global__ __launch_bounds__(256) void conv_w(const float* __restrict__ W,
                                              unsigned short* __restrict__ Wb) {
  size_t i = ((size_t)blockIdx.x * 256 + threadIdx.x) * 4;
  float4 v = *reinterpret_cast<const float4*>(W + i);
  ushort4 o;
  o.x = f2bf(v.x);
  o.y = f2bf(v.y);
  o.z = f2bf(v.z);
  o.w = f2bf(v.w);
  *reinterpret_cast<ushort4*>(Wb + i) = o;
}

// ---------------- stage 1: row-in-LDS (bf16) segment reduce, run-combined --
// (R6 structure, unchanged — best measured config: 2 blocks/CU, 137 µs total)
__global__ __launch_bounds__(1024, 8) void seg_reduce(
    const float* __restrict__ x, const unsigned* __restrict__ meta1,
    const unsigned* __restrict__ metaH, const unsigned short* __restrict__ metaG,
    const int* __restrict__ agg, unsigned short* __restrict__ y) {
  __shared__ unsigned short xrow[S_DIM];  // 64 KB (bf16)
  __shared__ float acc[G_DIM];            // 16 KB
  const int t = threadIdx.x;
  const int b = blockIdx.x;

#pragma unroll
  for (int i = 0; i < G_DIM / 1024; ++i) acc[t + i * 1024] = 0.0f;

  // stage full row as bf16: coalesced float4 load -> packed cvt -> 8B ds_write
  const float4* xg = reinterpret_cast<const float4*>(x + (size_t)b * S_DIM);
#pragma unroll
  for (int i = 0; i < S_DIM / 4 / 1024; ++i) {
    float4 v = xg[i * 1024 + t];
    unsigned short h0 = __builtin_bit_cast(unsigned short, (__bf16)v.x);
    unsigned short h1 = __builtin_bit_cast(unsigned short, (__bf16)v.y);
    unsigned short h2 = __builtin_bit_cast(unsigned short, (__bf16)v.z);
    unsigned short h3 = __builtin_bit_cast(unsigned short, (__bf16)v.w);
    uint2 p;
    p.x = (unsigned)h0 | ((unsigned)h1 << 16);
    p.y = (unsigned)h2 | ((unsigned)h3 << 16);
    *reinterpret_cast<uint2*>(&xrow[(i * 1024 + t) * 4]) = p;
  }
  __syncthreads();

  const int s0 = t * 32;
  const unsigned mrun = metaH[t];
  const bool firstPlain = (mrun & 1u) != 0;  // first run starts at s0
  int g = metaG[t];
  float sum = 0.0f;
  int nflush = 0;

  for (int h = 0; h < 2; ++h) {  // two halves of 16 elems
    const int sb = s0 + h * 16;
    uint4 ma = *reinterpret_cast<const uint4*>(meta1 + sb);
    uint4 mb = *reinterpret_cast<const uint4*>(meta1 + sb + 4);
    uint4 mc = *reinterpret_cast<const uint4*>(meta1 + sb + 8);
    uint4 md = *reinterpret_cast<const uint4*>(meta1 + sb + 12);
    unsigned m[16] = {ma.x, ma.y, ma.z, ma.w, mb.x, mb.y, mb.z, mb.w,
                      mc.x, mc.y, mc.z, mc.w, md.x, md.y, md.z, md.w};
    unsigned short xu[16];
#pragma unroll
    for (int j = 0; j < 16; ++j) xu[j] = xrow[m[j] & 0x7FFF];
    const unsigned mh = mrun >> (h * 16);
#pragma unroll
    for (int j = 0; j < 16; ++j) {
      if (h + j > 0 && (mh & (1u << j))) {  // run head: flush previous run
        if (nflush == 0 && !firstPlain) {
          lds_add(&acc[g], sum);  // first run extends into prev thread
        } else {
          acc[g] = sum;  // exclusively-owned run
        }
        ++nflush;
        sum = 0.0f;
        ++g;
      }
      float xv = __builtin_bit_cast(float, (unsigned)xu[j] << 16);
      float cm = __builtin_bit_cast(float, m[j] & 0xFFFF0000u);
      float v = (m[j] & 0x8000u) ? (xu[j] ? 1.0f : 0.0f) : xv * cm;
      sum += v;
    }
  }
  lds_add(&acc[g], sum);  // last run may extend into next thread

  // Drain asm ds_adds (invisible to compiler waitcnt model) before barrier.
  asm volatile("s_waitcnt lgkmcnt(0)" ::: "memory");
  __syncthreads();

#pragma unroll
  for (int i = 0; i < G_DIM / 1024; ++i) {
    int g2 = t + i * 1024;
    float v = acc[g2];
    if (agg[g2] == 1) v = (v > 0.0f) ? 1.0f : 0.0f;  // acc holds nnz count
    v = fmaxf(v, 0.0f);                               // relu
    y[(size_t)b * G_DIM + g2] = f2bf(v);
  }
}

// ---------------- stage 2a: split-K GEMM, f32 partials ---------------------
// part[kc][b][e] = sum_{g in chunk kc} y[b,g] * W[e,g].  Grid z = 4 K-chunks
// of 1024 -> 2048 blocks (8/CU): barrier drains of one block hide under
// other blocks' MFMA (m114 overlap), unlike the old 512-block 2/CU version.
__global__ __launch_bounds__(256) void gemm_bt(
    const unsigned short* __restrict__ A,   // y bf16 [B_DIM][G_DIM]
    const unsigned short* __restrict__ Bw,  // W bf16 [E_DIM][G_DIM]
    float* __restrict__ part) {             // [KSPLIT][B_DIM][E_DIM]
  __shared__ __align__(16) unsigned short As[64 * 64];  // 8 KB
  __shared__ __align__(16) unsigned short Bs[64 * 64];  // 8 KB
  const int t = threadIdx.x;
  const int lane = t & 63;
  const int wid = t >> 6;
  const int wr = wid >> 1;  // wave row (M)
  const int wc = wid & 1;   // wave col (N)
  const int row0 = blockIdx.y * 64;
  const int col0 = blockIdx.x * 64;
  const int kc = blockIdx.z;

  // staging: thread t covers LDS byte t*16 -> (row=t>>3, slot=t&7)
  const int r_ = t >> 3;  // 0..31
  const int s_ = t & 7;
  const int ksw = (s_ ^ (r_ & 7)) * 8;  // inverse-swizzled k offset (elements)
  const unsigned short* Ag0 = A + (size_t)(row0 + r_) * G_DIM + ksw;
  const unsigned short* Ag1 = A + (size_t)(row0 + r_ + 32) * G_DIM + ksw;
  const unsigned short* Bg0 = Bw + (size_t)(col0 + r_) * G_DIM + ksw;
  const unsigned short* Bg1 = Bw + (size_t)(col0 + r_ + 32) * G_DIM + ksw;

  char* AsB = (char*)As;
  char* BsB = (char*)Bs;
  char* dA0 = AsB + wid * 1024;          // wave-uniform LDS dst bases
  char* dA1 = AsB + 4096 + wid * 1024;
  char* dB0 = BsB + wid * 1024;
  char* dB1 = BsB + 4096 + wid * 1024;

  const int lm = lane & 15;
  const int lk = lane >> 4;  // 0..3

  f32x4 acc[2][2] = {};

  for (int kt = kc * KCHUNK; kt < (kc + 1) * KCHUNK; kt += 64) {
    async16(dA0, Ag0 + kt);
    async16(dA1, Ag1 + kt);
    async16(dB0, Bg0 + kt);
    async16(dB1, Bg1 + kt);
    __syncthreads();  // drains vmcnt before barrier
#pragma unroll
    for (int kk = 0; kk < 2; ++kk) {
      bf16x8 af[2], bfr[2];
#pragma unroll
      for (int m = 0; m < 2; ++m) {
        int row = wr * 32 + m * 16 + lm;
        int slot = (kk * 4 + lk) ^ (row & 7);
        af[m] = *(const bf16x8*)(AsB + row * 128 + slot * 16);
      }
#pragma unroll
      for (int n = 0; n < 2; ++n) {
        int row = wc * 32 + n * 16 + lm;
        int slot = (kk * 4 + lk) ^ (row & 7);
        bfr[n] = *(const bf16x8*)(BsB + row * 128 + slot * 16);
      }
#pragma unroll
      for (int m = 0; m < 2; ++m)
#pragma unroll
        for (int n = 0; n < 2; ++n)
          acc[m][n] = __builtin_amdgcn_mfma_f32_16x16x32_bf16(af[m], bfr[n],
                                                              acc[m][n], 0, 0, 0);
    }
    __syncthreads();  // protect LDS before next stage
  }

  // C/D layout: col = lane&15, row = (lane>>4)*4 + reg
  float* P = part + (size_t)kc * B_DIM * E_DIM;
#pragma unroll
  for (int m = 0; m < 2; ++m) {
    int r = row0 + wr * 32 + m * 16 + lk * 4;
#pragma unroll
    for (int n = 0; n < 2; ++n) {
      int c = col0 + wc * 32 + n * 16 + lm;
#pragma unroll
      for (int q = 0; q < 4; ++q) {
        P[(size_t)(r + q) * E_DIM + c] = acc[m][n][q];
      }
    }
  }
}

// ---------------- stage 2b: reduce split-K partials ------------------------
__global__ __launch_bounds__(256) void reduce_part(
    const float* __restrict__ part, float* __restrict__ C) {
  const size_t i = ((size_t)blockIdx.x * 256 + threadIdx.x) * 4;
  const size_t n = (size_t)B_DIM * E_DIM;
  float4 v0 = *reinterpret_cast<const float4*>(part + i);
  float4 v1 = *reinterpret_cast<const float4*>(part + n + i);
  float4 v2 = *reinterpret_cast<const float4*>(part + 2 * n + i);
  float4 v3 = *reinterpret_cast<const float4*>(part + 3 * n + i);
  float4 o;
  o.x = (v0.x + v1.x) + (v2.x + v3.x);
  o.y = (v0.y + v1.y) + (v2.y + v3.y);
  o.z = (v0.z + v1.z) + (v2.z + v3.z);
  o.w = (v0.w + v1.w) + (v2.w + v3.w);
  *reinterpret_cast<float4*>(C + i) = o;
}

extern "C" void kernel_launch(void* const* d_in, const int* in_sizes, int n_in,
                              void* d_out, int out_size, void* d_ws, size_t ws_size,
                              hipStream_t stream) {
  const float* x = (const float*)d_in[0];
  const float* W = (const float*)d_in[1];
  const float* w_elem = (const float*)d_in[2];
  const int* perm = (const int*)d_in[3];
  const int* segid = (const int*)d_in[4];
  const int* agg = (const int*)d_in[5];
  float* out = (float*)d_out;

  char* ws = (char*)d_ws;
  unsigned short* y = (unsigned short*)ws;  // B*G bf16 = 16 MB
  unsigned short* Wb =
      (unsigned short*)(ws + (size_t)B_DIM * G_DIM * 2);  // E*G bf16 = 8 MB
  float* part = (float*)(ws + (size_t)B_DIM * G_DIM * 2 +
                         (size_t)E_DIM * G_DIM * 2);  // 4*B*E f32 = 32 MB
  unsigned* meta1 = (unsigned*)((char*)part +
                                (size_t)KSPLIT * B_DIM * E_DIM * 4);
  unsigned* metaH = (unsigned*)((char*)meta1 + (size_t)S_DIM * 4);
  unsigned short* metaG = (unsigned short*)((char*)metaH + (S_DIM / 32) * 4);

  hipLaunchKernelGGL(setup_meta, dim3(S_DIM / 256), dim3(256), 0, stream,
                     w_elem, perm, segid, agg, meta1);
  hipLaunchKernelGGL(setup_runs, dim3((S_DIM / 32) / 256), dim3(256), 0,
                     stream, segid, metaH, metaG);
  hipLaunchKernelGGL(conv_w, dim3((E_DIM * G_DIM / 4) / 256), dim3(256), 0,
                     stream, W, Wb);
  hipLaunchKernelGGL(seg_reduce, dim3(B_DIM), dim3(1024), 0, stream, x, meta1,
                     metaH, metaG, agg, y);
  hipLaunchKernelGGL(gemm_bt, dim3(E_DIM / 64, B_DIM / 64, KSPLIT), dim3(256),
                     0, stream, y, Wb, part);
  hipLaunchKernelGGL(reduce_part,
                     dim3(((size_t)B_DIM * E_DIM / 4) / 256), dim3(256), 0,
                     stream, part, out);
}

// Round 10
// 126.018 us; speedup vs baseline: 1.2179x; 1.0319x over previous
//
#include <hip/hip_runtime.h>
#include <hip/hip_bf16.h>

#define B_DIM 2048
#define S_DIM 32768
#define G_DIM 4096
#define E_DIM 1024
#define KSPLIT 4
#define KCHUNK (G_DIM / KSPLIT)

typedef __bf16 bf16x8 __attribute__((ext_vector_type(8)));
typedef float f32x4 __attribute__((ext_vector_type(4)));

__device__ __forceinline__ unsigned short f2bf(float f) {
  unsigned int u = __builtin_bit_cast(unsigned int, f);
  u += 0x7FFFu + ((u >> 16) & 1u);   // round-to-nearest-even (no NaN inputs here)
  return (unsigned short)(u >> 16);
}

__device__ __forceinline__ float bfl(unsigned u) {
  return __builtin_bit_cast(float, u << 16);
}
__device__ __forceinline__ float bfh(unsigned u) {
  return __builtin_bit_cast(float, u & 0xFFFF0000u);
}

__device__ __forceinline__ void async16(void* lds, const void* g) {
  __builtin_amdgcn_global_load_lds(
      (const __attribute__((address_space(1))) unsigned int*)g,
      (__attribute__((address_space(3))) unsigned int*)lds, 16, 0, 0);
}

// ---------------- setup A: per-element packed meta --------------------------
// meta1[s] = perm[s] (15b) | orflag (bit15) | bf16(cm) (bits16-31)
__global__ __launch_bounds__(256) void setup_meta(
    const float* __restrict__ w_elem, const int* __restrict__ perm,
    const int* __restrict__ segid, const int* __restrict__ agg,
    unsigned* __restrict__ meta1) {
  int s = blockIdx.x * 256 + threadIdx.x;
  if (s >= S_DIM) return;
  int g = segid[s];
  int a = agg[g];
  float cm = (a == 0) ? 1.0f : (a == 2 ? w_elem[s] : 0.0f);
  meta1[s] = (unsigned)perm[s] | (a == 1 ? 0x8000u : 0u) |
             ((unsigned)f2bf(cm) << 16);
}

// ---------------- setup B: per-32-window run-head mask + first group -------
__global__ __launch_bounds__(256) void setup_runs(
    const int* __restrict__ segid, unsigned* __restrict__ metaH,
    unsigned short* __restrict__ metaG) {
  int t = blockIdx.x * 256 + threadIdx.x;
  if (t >= S_DIM / 32) return;
  int s0 = t * 32;
  int prev = (s0 == 0) ? -1 : segid[s0 - 1];
  unsigned m = 0;
#pragma unroll
  for (int c = 0; c < 8; ++c) {
    int4 gw = *reinterpret_cast<const int4*>(segid + s0 + c * 4);
    if (gw.x != prev) m |= 1u << (c * 4 + 0);
    if (gw.y != gw.x) m |= 1u << (c * 4 + 1);
    if (gw.z != gw.y) m |= 1u << (c * 4 + 2);
    if (gw.w != gw.z) m |= 1u << (c * 4 + 3);
    prev = gw.w;
  }
  metaH[t] = m;
  metaG[t] = (unsigned short)segid[s0];
}

// ---------------- W (f32, [E][G]) -> bf16 ----------------
__global__ __launch_bounds__(256) void conv_w(const float* __restrict__ W,
                                              unsigned short* __restrict__ Wb) {
  size_t i = ((size_t)blockIdx.x * 256 + threadIdx.x) * 4;
  float4 v = *reinterpret_cast<const float4*>(W + i);
  ushort4 o;
  o.x = f2bf(v.x);
  o.y = f2bf(v.y);
  o.z = f2bf(v.z);
  o.w = f2bf(v.w);
  *reinterpret_cast<ushort4*>(Wb + i) = o;
}

// ---------------- stage 1: row-in-LDS segment reduce, ATOMIC-FREE ----------
// R6 structure (2 blocks/CU) but boundary runs combined via a publish/forward-
// walk phase instead of ds_add_f32: zero LDS atomics, no lgkm drain hack.
// scr[] aliases the head of xrow (dead after the gather phase).
__global__ __launch_bounds__(1024, 8) void seg_reduce(
    const float* __restrict__ x, const unsigned* __restrict__ meta1,
    const unsigned* __restrict__ metaH, const unsigned short* __restrict__ metaG,
    const int* __restrict__ agg, unsigned short* __restrict__ y) {
  __shared__ __align__(16) unsigned short xrow[S_DIM];  // 64 KB (bf16)
  __shared__ float acc[G_DIM];                          // 16 KB
  float* scr = reinterpret_cast<float*>(xrow);  // 4 KB alias, valid post-walk
  const int t = threadIdx.x;
  const int b = blockIdx.x;

#pragma unroll
  for (int i = 0; i < G_DIM / 1024; ++i) acc[t + i * 1024] = 0.0f;

  // hoisted metadata (coalesced)
  const unsigned mrun = metaH[t];
  const unsigned nextH = (t < 1023) ? metaH[t + 1] : 1u;
  const bool fp = (mrun & 1u) != 0;  // head exactly at my window start
  int g = metaG[t];

  // stage full row as bf16: coalesced float4 load -> packed cvt -> 8B ds_write
  const float4* xg = reinterpret_cast<const float4*>(x + (size_t)b * S_DIM);
#pragma unroll
  for (int i = 0; i < S_DIM / 4 / 1024; ++i) {
    float4 v = xg[i * 1024 + t];
    unsigned short h0 = __builtin_bit_cast(unsigned short, (__bf16)v.x);
    unsigned short h1 = __builtin_bit_cast(unsigned short, (__bf16)v.y);
    unsigned short h2 = __builtin_bit_cast(unsigned short, (__bf16)v.z);
    unsigned short h3 = __builtin_bit_cast(unsigned short, (__bf16)v.w);
    uint2 p;
    p.x = (unsigned)h0 | ((unsigned)h1 << 16);
    p.y = (unsigned)h2 | ((unsigned)h3 << 16);
    *reinterpret_cast<uint2*>(&xrow[(i * 1024 + t) * 4]) = p;
  }
  __syncthreads();

  const int s0 = t * 32;
  float sum = 0.0f, lead = 0.0f;
  int nf = 0;

  for (int h = 0; h < 2; ++h) {  // two halves of 16 elems
    const int sb = s0 + h * 16;
    uint4 ma = *reinterpret_cast<const uint4*>(meta1 + sb);
    uint4 mb = *reinterpret_cast<const uint4*>(meta1 + sb + 4);
    uint4 mc = *reinterpret_cast<const uint4*>(meta1 + sb + 8);
    uint4 md = *reinterpret_cast<const uint4*>(meta1 + sb + 12);
    unsigned m[16] = {ma.x, ma.y, ma.z, ma.w, mb.x, mb.y, mb.z, mb.w,
                      mc.x, mc.y, mc.z, mc.w, md.x, md.y, md.z, md.w};
    unsigned short xu[16];
#pragma unroll
    for (int j = 0; j < 16; ++j) xu[j] = xrow[m[j] & 0x7FFF];
    const unsigned mh = mrun >> (h * 16);
#pragma unroll
    for (int j = 0; j < 16; ++j) {
      if (h + j > 0 && (mh & (1u << j))) {  // run head: close previous run
        if (nf == 0 && !fp) {
          lead = sum;  // continuation from a previous window: publish later
        } else {
          acc[g] = sum;  // run started & ended inside my window: exclusive
        }
        ++nf;
        sum = 0.0f;
        ++g;
      }
      float xv = bfl((unsigned)xu[j]);
      float cm = bfh(m[j]);
      float v = (m[j] & 0x8000u) ? (xu[j] ? 1.0f : 0.0f) : xv * cm;
      sum += v;
    }
  }

  __syncthreads();  // all gathers from xrow done -> safe to alias scr

  // publish my leading-run partial (full-window sum if I have no run head)
  scr[t] = fp ? 0.0f : (nf == 0 ? sum : lead);
  __syncthreads();

  // owner of each boundary-crossing run (the window holding its head) walks
  // forward collecting successors' published partials; single plain write.
  if (mrun != 0) {
    float tot = sum;  // my trailing partial
    unsigned fh = nextH;
    int k = t + 1;
    while (k < 1024) {
      tot += scr[k];
      if (fh) break;
      ++k;
      fh = metaH[k];  // rare path (P ~ 1.4% per extra step), L2-hot
    }
    acc[g] = tot;
  }
  __syncthreads();

#pragma unroll
  for (int i = 0; i < G_DIM / 1024; ++i) {
    int g2 = t + i * 1024;
    float v = acc[g2];
    if (agg[g2] == 1) v = (v > 0.0f) ? 1.0f : 0.0f;  // acc holds nnz count
    v = fmaxf(v, 0.0f);                               // relu
    y[(size_t)b * G_DIM + g2] = f2bf(v);
  }
}

// ---------------- stage 2a: split-K GEMM, bf16 partials --------------------
__global__ __launch_bounds__(256) void gemm_bt(
    const unsigned short* __restrict__ A,   // y bf16 [B_DIM][G_DIM]
    const unsigned short* __restrict__ Bw,  // W bf16 [E_DIM][G_DIM]
    unsigned short* __restrict__ part) {    // [KSPLIT][B_DIM][E_DIM] bf16
  __shared__ __align__(16) unsigned short As[64 * 64];  // 8 KB
  __shared__ __align__(16) unsigned short Bs[64 * 64];  // 8 KB
  const int t = threadIdx.x;
  const int lane = t & 63;
  const int wid = t >> 6;
  const int wr = wid >> 1;  // wave row (M)
  const int wc = wid & 1;   // wave col (N)
  const int row0 = blockIdx.y * 64;
  const int col0 = blockIdx.x * 64;
  const int kc = blockIdx.z;

  // staging: thread t covers LDS byte t*16 -> (row=t>>3, slot=t&7)
  const int r_ = t >> 3;  // 0..31
  const int s_ = t & 7;
  const int ksw = (s_ ^ (r_ & 7)) * 8;  // inverse-swizzled k offset (elements)
  const unsigned short* Ag0 = A + (size_t)(row0 + r_) * G_DIM + ksw;
  const unsigned short* Ag1 = A + (size_t)(row0 + r_ + 32) * G_DIM + ksw;
  const unsigned short* Bg0 = Bw + (size_t)(col0 + r_) * G_DIM + ksw;
  const unsigned short* Bg1 = Bw + (size_t)(col0 + r_ + 32) * G_DIM + ksw;

  char* AsB = (char*)As;
  char* BsB = (char*)Bs;
  char* dA0 = AsB + wid * 1024;          // wave-uniform LDS dst bases
  char* dA1 = AsB + 4096 + wid * 1024;
  char* dB0 = BsB + wid * 1024;
  char* dB1 = BsB + 4096 + wid * 1024;

  const int lm = lane & 15;
  const int lk = lane >> 4;  // 0..3

  f32x4 acc[2][2] = {};

  for (int kt = kc * KCHUNK; kt < (kc + 1) * KCHUNK; kt += 64) {
    async16(dA0, Ag0 + kt);
    async16(dA1, Ag1 + kt);
    async16(dB0, Bg0 + kt);
    async16(dB1, Bg1 + kt);
    __syncthreads();  // drains vmcnt before barrier
#pragma unroll
    for (int kk = 0; kk < 2; ++kk) {
      bf16x8 af[2], bfr[2];
#pragma unroll
      for (int m = 0; m < 2; ++m) {
        int row = wr * 32 + m * 16 + lm;
        int slot = (kk * 4 + lk) ^ (row & 7);
        af[m] = *(const bf16x8*)(AsB + row * 128 + slot * 16);
      }
#pragma unroll
      for (int n = 0; n < 2; ++n) {
        int row = wc * 32 + n * 16 + lm;
        int slot = (kk * 4 + lk) ^ (row & 7);
        bfr[n] = *(const bf16x8*)(BsB + row * 128 + slot * 16);
      }
#pragma unroll
      for (int m = 0; m < 2; ++m)
#pragma unroll
        for (int n = 0; n < 2; ++n)
          acc[m][n] = __builtin_amdgcn_mfma_f32_16x16x32_bf16(af[m], bfr[n],
                                                              acc[m][n], 0, 0, 0);
    }
    __syncthreads();  // protect LDS before next stage
  }

  // C/D layout: col = lane&15, row = (lane>>4)*4 + reg
  unsigned short* P = part + (size_t)kc * B_DIM * E_DIM;
#pragma unroll
  for (int m = 0; m < 2; ++m) {
    int r = row0 + wr * 32 + m * 16 + lk * 4;
#pragma unroll
    for (int n = 0; n < 2; ++n) {
      int c = col0 + wc * 32 + n * 16 + lm;
#pragma unroll
      for (int q = 0; q < 4; ++q) {
        P[(size_t)(r + q) * E_DIM + c] = f2bf(acc[m][n][q]);
      }
    }
  }
}

// ---------------- stage 2b: reduce bf16 split-K partials -------------------
__global__ __launch_bounds__(256) void reduce_part(
    const unsigned short* __restrict__ part, float* __restrict__ C) {
  const size_t i = ((size_t)blockIdx.x * 256 + threadIdx.x) * 8;
  const size_t n = (size_t)B_DIM * E_DIM;
  float e[8] = {};
#pragma unroll
  for (int p = 0; p < KSPLIT; ++p) {
    uint4 v = *reinterpret_cast<const uint4*>(part + p * n + i);
    unsigned w[4] = {v.x, v.y, v.z, v.w};
#pragma unroll
    for (int q = 0; q < 4; ++q) {
      e[2 * q] += bfl(w[q]);
      e[2 * q + 1] += bfh(w[q]);
    }
  }
  float4 o0 = {e[0], e[1], e[2], e[3]};
  float4 o1 = {e[4], e[5], e[6], e[7]};
  *reinterpret_cast<float4*>(C + i) = o0;
  *reinterpret_cast<float4*>(C + i + 4) = o1;
}

extern "C" void kernel_launch(void* const* d_in, const int* in_sizes, int n_in,
                              void* d_out, int out_size, void* d_ws, size_t ws_size,
                              hipStream_t stream) {
  const float* x = (const float*)d_in[0];
  const float* W = (const float*)d_in[1];
  const float* w_elem = (const float*)d_in[2];
  const int* perm = (const int*)d_in[3];
  const int* segid = (const int*)d_in[4];
  const int* agg = (const int*)d_in[5];
  float* out = (float*)d_out;

  char* ws = (char*)d_ws;
  unsigned short* y = (unsigned short*)ws;  // B*G bf16 = 16 MB
  unsigned short* Wb =
      (unsigned short*)(ws + (size_t)B_DIM * G_DIM * 2);  // E*G bf16 = 8 MB
  unsigned short* part =
      (unsigned short*)(ws + (size_t)B_DIM * G_DIM * 2 +
                        (size_t)E_DIM * G_DIM * 2);  // 4*B*E bf16 = 16 MB
  unsigned* meta1 =
      (unsigned*)((char*)part + (size_t)KSPLIT * B_DIM * E_DIM * 2);
  unsigned* metaH = (unsigned*)((char*)meta1 + (size_t)S_DIM * 4);
  unsigned short* metaG = (unsigned short*)((char*)metaH + (S_DIM / 32) * 4);

  hipLaunchKernelGGL(setup_meta, dim3(S_DIM / 256), dim3(256), 0, stream,
                     w_elem, perm, segid, agg, meta1);
  hipLaunchKernelGGL(setup_runs, dim3((S_DIM / 32) / 256), dim3(256), 0,
                     stream, segid, metaH, metaG);
  hipLaunchKernelGGL(conv_w, dim3((E_DIM * G_DIM / 4) / 256), dim3(256), 0,
                     stream, W, Wb);
  hipLaunchKernelGGL(seg_reduce, dim3(B_DIM), dim3(1024), 0, stream, x, meta1,
                     metaH, metaG, agg, y);
  hipLaunchKernelGGL(gemm_bt, dim3(E_DIM / 64, B_DIM / 64, KSPLIT), dim3(256),
                     0, stream, y, Wb, part);
  hipLaunchKernelGGL(reduce_part,
                     dim3(((size_t)B_DIM * E_DIM / 8) / 256), dim3(256), 0,
                     stream, part, out);
}